// Round 11
// baseline (44.979 us; speedup 1.0000x reference)
//
#include <hip/hip_runtime.h>
#include <math.h>

#define B_SZ 4096
#define D_SZ 32
#define M1_SZ 8
#define H_SZ 64
#define NSTEP 20
#define S1 21
#define BROWS 64   // rows per block
#define BT 128     // 2 waves; lane = [sgrp(1b)|b_lo(5b)]
#define KS 11      // steps per thread (sgrp0: s=0..10; sgrp1: s=11..21, 21 dead)

#ifndef M_PI
#define M_PI 3.14159265358979323846
#endif

#define LOG2E 1.44269504088896340736f
#define LN2   0.69314718055994530942f

__device__ __forceinline__ float fast_exp2(float x) {
#if __has_builtin(__builtin_amdgcn_exp2f)
  return __builtin_amdgcn_exp2f(x);
#else
  return exp2f(x);
#endif
}
__device__ __forceinline__ float fast_rcp(float x) {
#if __has_builtin(__builtin_amdgcn_rcpf)
  return __builtin_amdgcn_rcpf(x);
#else
  return 1.0f / x;
#endif
}

__global__ __launch_bounds__(BT) void umnn_main_kernel(
    const float* __restrict__ x, const float* __restrict__ x0,
    const float* __restrict__ We, const float* __restrict__ be,
    const float* __restrict__ W1, const float* __restrict__ b1,
    const float* __restrict__ W2, const float* __restrict__ b2,
    const float* __restrict__ scaling, float* __restrict__ out) {
  const int btile = blockIdx.x * BROWS;
  const int d = blockIdx.y;  // block-uniform -> weight addresses are SGPR-resident
  const int tid = threadIdx.x;

  __shared__ float xs[BROWS * 33];      // stride 33: conflict-free per-lane rows
  __shared__ float Wes[D_SZ * M1_SZ];   // [c][m]; uniform-addr broadcast reads
  __shared__ float bes[M1_SZ];
  __shared__ float steps_ext[S1 + 1];   // [21] = 1.0 (dead slot)
  __shared__ float ccw_ext[S1 + 1];     // [21] = 0.0

  // ---- staging (per-lane data only; weights stay in global for s_load) ----
  {
#pragma unroll
    for (int k = 0; k < 16; ++k) {  // x tile, stride 33
      int idx = tid + k * BT;
      int r = idx >> 5, c = idx & 31;
      xs[r * 33 + c] = x[(size_t)btile * D_SZ + idx];
    }
    {
      int idx = tid;       int m = idx >> 5, c = idx & 31;
      Wes[c * 8 + m] = We[(m * D_SZ + d) * D_SZ + c];
      idx = tid + BT;      m = idx >> 5;  c = idx & 31;
      Wes[c * 8 + m] = We[(m * D_SZ + d) * D_SZ + c];
    }
    if (tid < M1_SZ) bes[tid] = be[tid * D_SZ + d];
    if (tid < S1) {  // fp32 Clenshaw-Curtis (lenient threshold)
      steps_ext[tid] = cosf((float)tid * ((float)M_PI / 20.f));
      float acc = 0.f;
#pragma unroll
      for (int k = 0; k <= 10; ++k) {
        float w = (k == 0) ? 1.f : 2.f / (1.f - 4.f * (float)(k * k));
        float c = cosf((float)(k * tid) * ((float)M_PI / 10.f));
        float lam = (tid == 0 || tid == NSTEP) ? 0.5f * c : c;
        acc += w * lam;
      }
      ccw_ext[tid] = 0.1f * acc;
    }
    if (tid == S1) { steps_ext[S1] = 1.f; ccw_ext[S1] = 0.f; }
  }
  __syncthreads();

  const int lane = tid & 63;
  const int b_lo = lane & 31;
  const int sgrp = lane >> 5;                    // 0: s 0..10, 1: s 11..21
  const int b_local = ((tid >> 6) << 5) | b_lo;  // 0..63
  const int b = btile + b_local;
  const float* xrow = &xs[b_local * 33];
  const float x0b = x0[(size_t)b * D_SZ + d];

  // block-uniform weight bases (SGPR)
  const float* W1d = W1 + d * (M1_SZ + 1) * H_SZ;  // [i][h]
  const float* W2d = W2 + d * H_SZ;
  const float* b1d = b1 + d * H_SZ;
  const float b2v = b2[d];                          // s_load
  const float scal = fast_exp2(scaling[d] * LOG2E); // s_load + 1 exp

  // ---- masked encoder (x2 redundancy across sgrp) ----
  float a[M1_SZ];
#pragma unroll
  for (int m = 0; m < M1_SZ; ++m) a[m] = bes[m];
  for (int c = 0; c < d; ++c) {  // wave-uniform trip count
    float xc = xrow[c];
#pragma unroll
    for (int m = 0; m < M1_SZ; ++m) a[m] = fmaf(xc, Wes[c * 8 + m], a[m]);
  }
  float hm[M1_SZ];
#pragma unroll
  for (int m = 0; m < M1_SZ; ++m) {  // tanh via exp2 + rcp
    float t = fast_exp2(a[m] * (2.f * LOG2E));
    hm[m] = 1.f - 2.f * fast_rcp(t + 1.f);
  }
  const float hm0 = hm[0];

  const float xb = xrow[d];
  const float dxe = xb - x0b;
  const float xc1 = 0.5f * dxe;
  const float xc0 = x0b + xc1;

  const int sbase = sgrp * KS;
  float XsL[KS];  // log2-scaled quadrature points (weights stay natural)
#pragma unroll
  for (int k = 0; k < KS; ++k)
    XsL[k] = fmaf(xc1, steps_ext[sbase + k], xc0) * LOG2E;

  // ---- main loop: all 64 h, my 11 steps; weights via scalar loads ----
  float acc[KS];
#pragma unroll
  for (int k = 0; k < KS; ++k) acc[k] = b2v;
  float w2s = 0.f;  // per-thread sum(w2) -> folds elu "-1" at the end

  for (int hg = 0; hg < 16; ++hg) {
    const int h0 = hg * 4;
    const float4 b1v = *reinterpret_cast<const float4*>(b1d + h0);  // s_load
    const float4 w1v = *reinterpret_cast<const float4*>(W1d + h0);  // W1[d][0][h]
    const float4 w2v = *reinterpret_cast<const float4*>(W2d + h0);
    float4 bse = b1v;
#pragma unroll
    for (int m = 0; m < M1_SZ; ++m) {  // base += hm[m] * W1[d][m+1][h]
      const float4 wm = *reinterpret_cast<const float4*>(W1d + (m + 1) * H_SZ + h0);
      bse.x = fmaf(hm[m], wm.x, bse.x);
      bse.y = fmaf(hm[m], wm.y, bse.y);
      bse.z = fmaf(hm[m], wm.z, bse.z);
      bse.w = fmaf(hm[m], wm.w, bse.w);
    }
    const float bsa[4] = {bse.x * LOG2E, bse.y * LOG2E, bse.z * LOG2E, bse.w * LOG2E};
    const float w1a[4] = {w1v.x, w1v.y, w1v.z, w1v.w};
    const float w2a[4] = {w2v.x, w2v.y, w2v.z, w2v.w};
    w2s += (w2a[0] + w2a[1]) + (w2a[2] + w2a[3]);
#pragma unroll
    for (int k = 0; k < KS; ++k) {
      float ak = acc[k];
#pragma unroll
      for (int j = 0; j < 4; ++j) {
        float preL = fmaf(XsL[k], w1a[j], bsa[j]);  // log2-domain preact
        float e = fmaf(fmaxf(preL, 0.f), LN2, fast_exp2(fminf(preL, 0.f)));  // elu+1
        ak = fmaf(e, w2a[j], ak);
      }
      acc[k] = ak;
    }
  }

  // ---- per-step second elu + quadrature partial, then one shfl ----
  float dzsum = 0.f;
#pragma unroll
  for (int k = 0; k < KS; ++k) {
    float pL = (acc[k] - w2s) * LOG2E;
    float dz = fmaf(fmaxf(pL, 0.f), LN2, fast_exp2(fminf(pL, 0.f)));  // elu+1
    dzsum = fmaf(ccw_ext[sbase + k], dz, dzsum);
  }
  dzsum += __shfl_xor(dzsum, 32);  // combine the two step-halves

  if (sgrp == 0) out[(size_t)b * D_SZ + d] = scal * fmaf(xc1, dzsum, hm0);
}

extern "C" void kernel_launch(void* const* d_in, const int* in_sizes, int n_in,
                              void* d_out, int out_size, void* d_ws, size_t ws_size,
                              hipStream_t stream) {
  const float* x       = (const float*)d_in[0];
  const float* x0      = (const float*)d_in[1];
  const float* We      = (const float*)d_in[2];
  const float* be      = (const float*)d_in[3];
  const float* W1      = (const float*)d_in[4];
  const float* b1      = (const float*)d_in[5];
  const float* W2      = (const float*)d_in[6];
  const float* b2      = (const float*)d_in[7];
  const float* scaling = (const float*)d_in[8];
  float* out = (float*)d_out;

  dim3 grid(B_SZ / BROWS, D_SZ);
  umnn_main_kernel<<<grid, BT, 0, stream>>>(x, x0, We, be, W1, b1, W2, b2,
                                            scaling, out);
}